// Round 6
// baseline (491.622 us; speedup 1.0000x reference)
//
#include <hip/hip_runtime.h>
#include <cstdint>
#include <cstddef>

#define MDIM 8192
#define NDIM 4096
#define KDIM 4096

// NOTE: second resubmission — rounds 3 and 5 both died with "MI355X container
// failed twice" (infra flake; round 3's kernel passed unchanged on round 4).
// This kernel (m201 dual-barrier schedule + merged prepass) is still
// unmeasured. Full hazard audit in the gemm256_kernel comment.

typedef __attribute__((ext_vector_type(8))) __bf16 bf16x8;
typedef __attribute__((ext_vector_type(4))) float floatx4;

typedef __attribute__((address_space(3))) void lds_t;
typedef __attribute__((address_space(1))) void glb_t;

__device__ __forceinline__ unsigned short f32_to_bf16(float f) {
  unsigned int u = __float_as_uint(f);
  u += 0x7FFFu + ((u >> 16) & 1u);   // RNE
  return (unsigned short)(u >> 16);
}

// e2m1 magnitude for code c in 0..7: {0,0.5,1,1.5,2,3,4,6}
__device__ __forceinline__ float fp4_mag(int c) {
  int e = (c >> 1) & 3, m = c & 1;
  int sh = e ? (e - 1) : 0;
  return e ? 0.5f * (float)((2 + m) << sh) : 0.5f * (float)m;
}

// ---------------- merged prepass: conv (x->bf16) || dequant (w->bf16) -------
// Independent jobs on disjoint block ranges run CONCURRENTLY in one dispatch
// (previously two stream-serialized launches, ~30us + ~11us back-to-back).
#define CONV_BLOCKS 16384      // (MDIM*KDIM/8)/256
#define DEQ_BLOCKS  4096       // (NDIM*KDIM/16)/256
__global__ __launch_bounds__(256) void prep_kernel(const float* __restrict__ x,
                                                   unsigned short* __restrict__ xb,
                                                   const int* __restrict__ packed,
                                                   const float* __restrict__ scales,
                                                   unsigned short* __restrict__ wb) {
  if (blockIdx.x < CONV_BLOCKS) {
    const int t = blockIdx.x * 256 + threadIdx.x;   // 8 elems each
    const float4* src = (const float4*)x + (size_t)t * 2;
    float4 a = src[0], b = src[1];
    union { unsigned short us[8]; uint4 u4; } o;
    o.us[0] = f32_to_bf16(a.x); o.us[1] = f32_to_bf16(a.y);
    o.us[2] = f32_to_bf16(a.z); o.us[3] = f32_to_bf16(a.w);
    o.us[4] = f32_to_bf16(b.x); o.us[5] = f32_to_bf16(b.y);
    o.us[6] = f32_to_bf16(b.z); o.us[7] = f32_to_bf16(b.w);
    ((uint4*)xb)[t] = o.u4;
  } else {
    const int t = (blockIdx.x - CONV_BLOCKS) * 256 + threadIdx.x;  // one 16-elem block
    const int4* p = (const int4*)packed + (size_t)t * 2;
    int4 pa = p[0], pb = p[1];
    float s = scales[t];
    int bytes[8] = {pa.x, pa.y, pa.z, pa.w, pb.x, pb.y, pb.z, pb.w};
    union { unsigned short us[16]; uint4 u4[2]; } o;
#pragma unroll
    for (int i = 0; i < 8; ++i) {
      int by = bytes[i] & 255;
      int hi = by >> 4, lo = by & 15;               // even idx = high nibble
      float vh = fp4_mag(hi & 7) * s; if (hi & 8) vh = -vh;
      float vl = fp4_mag(lo & 7) * s; if (lo & 8) vl = -vl;
      o.us[2 * i]     = f32_to_bf16(vh);
      o.us[2 * i + 1] = f32_to_bf16(vl);
    }
    uint4* dst = (uint4*)(wb + (size_t)t * 16);
    dst[0] = o.u4[0]; dst[1] = o.u4[1];
  }
}

// ---------------- main GEMM: C[M,N] = A[M,K] * B[N,K]^T + bias ----------------
// 256x256 tile, BK=32, 8 waves (2x4), 4-deep LDS ring (128 KiB).
// m201-faithful dual-barrier phase schedule (learn_hip-verified 62% MfmaUtil):
//   PH_A(T): {8 ds_reads (af0-3,bfv0-3 of buf T) ; stage(T+3,A-half) ;
//             s_barrier ; lgkmcnt(0)+sched_barrier ; setprio(1) ; 16 MFMA
//             acc[0..3] ; setprio(0) ; vmcnt(6) ; s_barrier}
//   PH_B(T): {4 ds_reads (af4-7) ; stage(T+3,B-half) ; s_barrier ;
//             lgkmcnt(0)+sched_barrier ; setprio(1) ; 16 MFMA acc[4..7] ;
//             setprio(0) ; s_barrier}
// Counted vmcnt(6) once per K-tile, never 0 in the main loop (T4).
// Hazards: buf[T] readiness collectively confirmed at PH_A(T-1)'s vmcnt(6)+
// barrier (T+1 landed there => T landed earlier). stage(T+3) overwrites
// buf[(T-1)&3]; its last reads (PH_B(T-1) af, PH_A(T-1) bfv) are drained by
// lgkmcnt(0) before the MFMA that precedes the barrier preceding the stage
// issue -> no WAR. vmcnt(6) count: outstanding <= T+1(4)+T+2(4)+T+3A(2)=10,
// wait-to-6 drains exactly tile T+1. Epilogue drains 4 -> 0.
//
// Swizzle (verified r1, 0 bank conflicts): LDS slot byte d holds tile byte
// b = d ^ (((d>>7)&7)<<4); staging pre-swizzles the GLOBAL source address
// (global_load_lds dest must stay linear), reads XOR the same function.
__global__ __launch_bounds__(512, 2) void gemm256_kernel(const __bf16* __restrict__ A,
                                                         const __bf16* __restrict__ B,
                                                         const float* __restrict__ bias,
                                                         float* __restrict__ C) {
  __shared__ __bf16 ldsbuf[65536];          // 128 KiB = A[4][8192] + B[4][8192]
  __bf16* As = ldsbuf;
  __bf16* Bs = ldsbuf + 32768;

  const int t = threadIdx.x;
  const int wave = t >> 6, lane = t & 63;
  const int quad = lane >> 4, r16 = lane & 15;
  const int wr = wave >> 2, wc = wave & 3;  // 2 (M) x 4 (N) wave grid

  // T1: XCD swizzle. 512 wgs, 8 XCDs -> 64 wgs/XCD; n-fastest inside an XCD.
  const int bid = blockIdx.x;
  const int wg = (bid & 7) * 64 + (bid >> 3);
  const int m0 = (wg >> 4) * 256, n0 = (wg & 15) * 256;

  // ---- staging source addresses (inverse-swizzled global, linear LDS dest) ----
  const int swzS = ((t >> 3) & 7) << 4;
  const int b0 = (t * 16) ^ swzS;            // load j=0: slot d = t*16
  const int b1 = (8192 + t * 16) ^ swzS;     // load j=1: slot d = 8192 + t*16
  const int row0 = b0 >> 6, col0 = (b0 & 63) >> 1;
  const int row1 = b1 >> 6, col1 = (b1 & 63) >> 1;   // row1 in [128,256)

  const __bf16* pa0 = A + (size_t)(m0 + row0) * KDIM + col0;
  const __bf16* pa1 = A + (size_t)(m0 + row1) * KDIM + col1;
  const __bf16* pb0 = B + (size_t)(n0 + row0) * KDIM + col0;
  const __bf16* pb1 = B + (size_t)(n0 + row1) * KDIM + col1;

  // ---- swizzled LDS read offsets (element units) ----
  const int swzR = ((r16 >> 1) & 7) << 4;
  const int offAe = ((((wr * 128 + r16) * 64) + quad * 16) ^ swzR) >> 1;
  const int offBe = ((((wc * 64  + r16) * 64) + quad * 16) ^ swzR) >> 1;

  floatx4 acc[8][4] = {};
  bf16x8 af[4], bfv[4];

  // ---- prologue: stage tiles 0,1,2 ----
#pragma unroll
  for (int p = 0; p < 3; ++p) {
    __bf16* _ab = As + p * 8192;
    __bf16* _bb = Bs + p * 8192;
    __builtin_amdgcn_global_load_lds((const glb_t*)(pa0 + p * 32), (lds_t*)(_ab + wave * 512), 16, 0, 0);
    __builtin_amdgcn_global_load_lds((const glb_t*)(pa1 + p * 32), (lds_t*)(_ab + 4096 + wave * 512), 16, 0, 0);
    __builtin_amdgcn_global_load_lds((const glb_t*)(pb0 + p * 32), (lds_t*)(_bb + wave * 512), 16, 0, 0);
    __builtin_amdgcn_global_load_lds((const glb_t*)(pb1 + p * 32), (lds_t*)(_bb + 4096 + wave * 512), 16, 0, 0);
  }
  asm volatile("s_waitcnt vmcnt(8)" ::: "memory");   // tile 0 fully landed
  __builtin_amdgcn_s_barrier();

  const __bf16* sa0 = pa0 + 96;   // staging cursor: tile 3
  const __bf16* sa1 = pa1 + 96;
  const __bf16* sb0 = pb0 + 96;
  const __bf16* sb1 = pb1 + 96;

#define VM6 asm volatile("s_waitcnt vmcnt(6)" ::: "memory")
#define VM4 asm volatile("s_waitcnt vmcnt(4)" ::: "memory")
#define VM0 asm volatile("s_waitcnt vmcnt(0)" ::: "memory")
#define VMNONE (void)0

#define PH_A(TT, DO_STAGE, VMASM) do {                                            \
    const __bf16* _a = As + ((TT) & 3) * 8192;                                    \
    const __bf16* _b = Bs + ((TT) & 3) * 8192;                                    \
    __bf16* _sa = As + (((TT) + 3) & 3) * 8192;                                   \
    _Pragma("unroll")                                                             \
    for (int i = 0; i < 4; ++i) af[i]  = *(const bf16x8*)(_a + offAe + i * 512);  \
    _Pragma("unroll")                                                             \
    for (int j = 0; j < 4; ++j) bfv[j] = *(const bf16x8*)(_b + offBe + j * 512);  \
    if (DO_STAGE) {                                                               \
      __builtin_amdgcn_global_load_lds((const glb_t*)sa0, (lds_t*)(_sa + wave * 512), 16, 0, 0);        \
      __builtin_amdgcn_global_load_lds((const glb_t*)sa1, (lds_t*)(_sa + 4096 + wave * 512), 16, 0, 0); \
    }                                                                             \
    __builtin_amdgcn_s_barrier();                                                 \
    asm volatile("s_waitcnt lgkmcnt(0)" ::: "memory");                            \
    __builtin_amdgcn_sched_barrier(0);                                            \
    __builtin_amdgcn_s_setprio(1);                                                \
    _Pragma("unroll")                                                             \
    for (int i = 0; i < 4; ++i) {                                                 \
      _Pragma("unroll")                                                           \
      for (int j = 0; j < 4; ++j)                                                 \
        acc[i][j] = __builtin_amdgcn_mfma_f32_16x16x32_bf16(af[i], bfv[j], acc[i][j], 0, 0, 0); \
    }                                                                             \
    __builtin_amdgcn_s_setprio(0);                                                \
    VMASM;                                                                        \
    __builtin_amdgcn_s_barrier();                                                 \
  } while (0)

#define PH_B(TT, DO_STAGE) do {                                                   \
    const __bf16* _a = As + ((TT) & 3) * 8192;                                    \
    __bf16* _sb = Bs + (((TT) + 3) & 3) * 8192;                                   \
    _Pragma("unroll")                                                             \
    for (int i = 0; i < 4; ++i) af[i] = *(const bf16x8*)(_a + offAe + (4 + i) * 512); \
    if (DO_STAGE) {                                                               \
      __builtin_amdgcn_global_load_lds((const glb_t*)sb0, (lds_t*)(_sb + wave * 512), 16, 0, 0);        \
      __builtin_amdgcn_global_load_lds((const glb_t*)sb1, (lds_t*)(_sb + 4096 + wave * 512), 16, 0, 0); \
    }                                                                             \
    __builtin_amdgcn_s_barrier();                                                 \
    asm volatile("s_waitcnt lgkmcnt(0)" ::: "memory");                            \
    __builtin_amdgcn_sched_barrier(0);                                            \
    __builtin_amdgcn_s_setprio(1);                                                \
    _Pragma("unroll")                                                             \
    for (int i = 0; i < 4; ++i) {                                                 \
      _Pragma("unroll")                                                           \
      for (int j = 0; j < 4; ++j)                                                 \
        acc[4 + i][j] = __builtin_amdgcn_mfma_f32_16x16x32_bf16(af[i], bfv[j], acc[4 + i][j], 0, 0, 0); \
    }                                                                             \
    __builtin_amdgcn_s_setprio(0);                                                \
    __builtin_amdgcn_s_barrier();                                                 \
  } while (0)

  // Main loop: tiles 0..124 stage tile T+3; vmcnt(6) once per tile in PH_A.
  for (int T = 0; T < 125; ++T) {
    PH_A(T, true, VM6);
    PH_B(T, true);
    sa0 += 32; sa1 += 32; sb0 += 32; sb1 += 32;
  }
  // Epilogue: 125 waits tile 126 (VM4), 126 waits tile 127 (VM0), 127 free.
  PH_A(125, false, VM4);
  PH_B(125, false);
  PH_A(126, false, VM0);
  PH_B(126, false);
  PH_A(127, false, VMNONE);
  PH_B(127, false);

#undef PH_A
#undef PH_B
#undef VM6
#undef VM4
#undef VM0
#undef VMNONE

  // epilogue: C/D layout col = lane&15, row = quad*4 + reg
  float bv[4];
#pragma unroll
  for (int j = 0; j < 4; ++j) bv[j] = bias[n0 + wc * 64 + j * 16 + r16];
#pragma unroll
  for (int i = 0; i < 8; ++i) {
    const int gm = m0 + wr * 128 + i * 16 + quad * 4;
#pragma unroll
    for (int j = 0; j < 4; ++j) {
      float* cp = C + (size_t)gm * NDIM + (n0 + wc * 64 + j * 16 + r16);
#pragma unroll
      for (int r = 0; r < 4; ++r)
        cp[(size_t)r * NDIM] = acc[i][j][r] + bv[j];
    }
  }
}

// ---------------- fallback (ws too small): fused naive ----------------
__global__ __launch_bounds__(256) void fused_fallback(const float* __restrict__ x,
                                                      const int* __restrict__ packed,
                                                      const float* __restrict__ scales,
                                                      const float* __restrict__ bias,
                                                      float* __restrict__ out) {
  const int n = blockIdx.x * 256 + threadIdx.x;
  const int m = blockIdx.y;
  const float* xr = x + (size_t)m * KDIM;
  const int* pr = packed + (size_t)n * (KDIM / 2);
  const float* sc = scales + (size_t)n * (KDIM / 16);
  float acc = 0.f;
  for (int kb = 0; kb < KDIM / 16; ++kb) {
    float s = sc[kb];
    float part = 0.f;
#pragma unroll
    for (int i = 0; i < 8; ++i) {
      int by = pr[kb * 8 + i] & 255;
      int hi = by >> 4, lo = by & 15;
      float vh = fp4_mag(hi & 7); if (hi & 8) vh = -vh;
      float vl = fp4_mag(lo & 7); if (lo & 8) vl = -vl;
      part += xr[kb * 16 + 2 * i] * vh + xr[kb * 16 + 2 * i + 1] * vl;
    }
    acc += s * part;
  }
  out[(size_t)m * NDIM + n] = acc + bias[n];
}

extern "C" void kernel_launch(void* const* d_in, const int* in_sizes, int n_in,
                              void* d_out, int out_size, void* d_ws, size_t ws_size,
                              hipStream_t stream) {
  const float* x      = (const float*)d_in[0];
  const int*   packed = (const int*)d_in[1];
  const float* scales = (const float*)d_in[2];
  const float* bias   = (const float*)d_in[3];
  float* out = (float*)d_out;

  const size_t needA = (size_t)MDIM * KDIM * 2;   // 64 MB bf16 x
  const size_t needW = (size_t)NDIM * KDIM * 2;   // 32 MB bf16 w

  if (ws_size >= needA + needW) {
    unsigned short* xb = (unsigned short*)d_ws;
    unsigned short* wb = (unsigned short*)((char*)d_ws + needA);
    prep_kernel<<<CONV_BLOCKS + DEQ_BLOCKS, 256, 0, stream>>>(x, xb, packed, scales, wb);
    dim3 grid((MDIM / 256) * (NDIM / 256));       // 512 wgs, XCD-swizzled in-kernel
    gemm256_kernel<<<grid, 512, 0, stream>>>((const __bf16*)xb, (const __bf16*)wb, bias, out);
  } else {
    dim3 grid(NDIM / 256, MDIM);
    fused_fallback<<<grid, 256, 0, stream>>>(x, packed, scales, bias, out);
  }
}